// Round 15
// baseline (156.451 us; speedup 1.0000x reference)
//
#include <hip/hip_runtime.h>
#include <hip/hip_bf16.h>

#define TPB 256
#define CTPB 512

using f32x4  = __attribute__((ext_vector_type(4))) float;
using bf16x8 = __attribute__((ext_vector_type(8))) short;

// Problem constants (B=4096, L=32, E=512, D=64)
static constexpr int BB = 4096;

// Workspace layout (bytes)
static constexpr size_t OFF_AHI  = 0;                        // a_hi [B][512] bf16 = 4 MB
static constexpr size_t OFF_D1   = 8388608;                  // d1 [B] f32 = 16 KB
static constexpr size_t OFF_H1   = OFF_D1 + 16384;           // hist u32[2048] = 8 KB
static constexpr size_t OFF_GS1  = OFF_H1 + 8192;            // gsum f64[2048] = 16 KB
static constexpr size_t OFF_L2P  = OFF_GS1 + 16384;          // loss2 partials f64[1024]
static constexpr size_t OFF_L3P  = OFF_L2P + 8192;           // loss3 partials f64[1024]
static constexpr size_t OFF_HS   = OFF_L3P + 8192;           // h1hi,h1lo,h2hi,h2lo bf16 [B][64]
static constexpr size_t HS_ONE   = (size_t)BB * 64 * 2;      // 512 KB
static constexpr size_t ZERO_OFF = OFF_H1;
static constexpr size_t ZERO_LEN = OFF_L2P - OFF_H1;         // 24576 B (hist + gsum only)

// ---------------- helpers ----------------
__device__ __forceinline__ void bsplit(float x, unsigned short& h, unsigned short& l)
{
    unsigned b = __float_as_uint(x);
    unsigned r = (b + 0x7FFFu + ((b >> 16) & 1u)) >> 16;       // rne bf16
    h = (unsigned short)r;
    float hf = __uint_as_float(r << 16);
    float lof = x - hf;                                        // exact in f32
    unsigned b2 = __float_as_uint(lof);
    unsigned r2 = (b2 + 0x7FFFu + ((b2 >> 16) & 1u)) >> 16;
    l = (unsigned short)r2;
}

__device__ __forceinline__ unsigned short b2h(float x)
{
    unsigned b = __float_as_uint(x);
    return (unsigned short)((b + 0x7FFFu + ((b >> 16) & 1u)) >> 16);
}

__device__ __forceinline__ void gload16(const void* g, void* l)
{
    __builtin_amdgcn_global_load_lds((const __attribute__((address_space(1))) void*)g,
                                     (__attribute__((address_space(3))) void*)l,
                                     16, 0, 0);
}

// ---------------- front: prep (blocks 0..2047, 2 rows each) + small (2048..3071) + zero (3072..3079) ----------------
__global__ __launch_bounds__(TPB) void front_k(
    const float* __restrict__ caps, const float* __restrict__ sim,
    unsigned short* __restrict__ ahi,
    const float* __restrict__ h1f, const float* __restrict__ h2f,
    unsigned short* __restrict__ h1hi, unsigned short* __restrict__ h1lo,
    unsigned short* __restrict__ h2hi, unsigned short* __restrict__ h2lo,
    float* __restrict__ d1, const float* __restrict__ sv,
    const float* __restrict__ sv2, double* __restrict__ l2part,
    double* __restrict__ l3part, char* __restrict__ base)
{
    const int blk = (int)blockIdx.x;
    const int tid = threadIdx.x;
    __shared__ float sm2[2][32];
    __shared__ float w2[2][32];
    __shared__ float red4[4];
    __shared__ float nrm2[2];
    __shared__ double r2[4], r3[4];

    if (blk < 2048) {
        // ---- prep: 2 rows/block, float4 caps loads, dual accumulators (chain break) ----
        const int g  = tid >> 7;          // 0..1 row group
        const int lt = tid & 127;         // 0..127 within group
        const int b  = (blk << 1) + g;
        if (lt < 32) sm2[g][lt] = sim[b * 32 + lt];
        __syncthreads();
        if (lt < 32) {
            float m = -1e30f;
            for (int l = 0; l < 32; ++l) m = fmaxf(m, sm2[g][l]);
            float ssum = 0.f;
            for (int l = 0; l < 32; ++l) ssum += expf(sm2[g][l] - m);
            w2[g][lt] = expf(sm2[g][lt] - m) / ssum;
        }
        __syncthreads();
        const float4* cb4 = (const float4*)caps + (size_t)b * 4096;  // 32*512/4
        float ax = 0.f, ay = 0.f, az = 0.f, aw = 0.f;   // even l
        float bx = 0.f, by = 0.f, bz = 0.f, bw = 0.f;   // odd l
        #pragma unroll 4
        for (int l = 0; l < 32; l += 2) {
            float wl0 = w2[g][l], wl1 = w2[g][l + 1];
            float4 v0 = cb4[l * 128 + lt];
            float4 v1 = cb4[(l + 1) * 128 + lt];
            ax = fmaf(wl0, v0.x, ax); ay = fmaf(wl0, v0.y, ay);
            az = fmaf(wl0, v0.z, az); aw = fmaf(wl0, v0.w, aw);
            bx = fmaf(wl1, v1.x, bx); by = fmaf(wl1, v1.y, by);
            bz = fmaf(wl1, v1.z, bz); bw = fmaf(wl1, v1.w, bw);
        }
        float cx = ax + bx, cy = ay + by, cz = az + bz, cw = aw + bw;
        float ss = cx * cx + cy * cy + cz * cz + cw * cw;
        #pragma unroll
        for (int off = 32; off; off >>= 1) ss += __shfl_down(ss, off, 64);
        if ((tid & 63) == 0) red4[tid >> 6] = ss;
        __syncthreads();
        if (lt == 0) nrm2[g] = sqrtf(red4[2 * g] + red4[2 * g + 1]);
        __syncthreads();
        float inv = 1.0f / fmaxf(nrm2[g], 1e-5f);
        ushort4 o;
        o.x = b2h(cx * inv); o.y = b2h(cy * inv); o.z = b2h(cz * inv); o.w = b2h(cw * inv);
        *(ushort4*)&ahi[(size_t)b * 512 + lt * 4] = o;
    } else if (blk < 3072) {
        // ---- small: splith + diag + loss2/loss3 partials (4 rows / block) ----
        const int pb   = blk - 2048;
        const int row  = (pb << 2) + (tid >> 6);
        const int lane = tid & 63;
        const int i    = (row << 6) + lane;
        float x1 = h1f[i], x2 = h2f[i];
        unsigned short h, l;
        bsplit(x1, h, l); h1hi[i] = h; h1lo[i] = l;
        bsplit(x2, h, l); h2hi[i] = h; h2lo[i] = l;
        float p = x1 * x2;
        #pragma unroll
        for (int m = 32; m; m >>= 1) p += __shfl_xor(p, m, 64);
        if (lane == 0) d1[row] = p;
        float xq = x1 - 0.5f;
        double s2 = (double)(xq * xq);
        #pragma unroll
        for (int m = 32; m; m >>= 1) s2 += __shfl_xor(s2, m, 64);
        float xt = sv[i] / 0.1f;
        float xs = sv2[i] / 0.1f;
        float mt = xt, ms = xs;
        #pragma unroll
        for (int m = 32; m; m >>= 1) {
            mt = fmaxf(mt, __shfl_xor(mt, m, 64));
            ms = fmaxf(ms, __shfl_xor(ms, m, 64));
        }
        float et = expf(xt - mt), es = expf(xs - ms);
        float sst = et, sss = es;
        #pragma unroll
        for (int m = 32; m; m >>= 1) { sst += __shfl_xor(sst, m, 64); sss += __shfl_xor(sss, m, 64); }
        float pt = (xt - mt) - logf(sst);
        float ps = (xs - ms) - logf(sss);
        double d3 = (double)((et / sst) * (pt - ps));
        #pragma unroll
        for (int m = 32; m; m >>= 1) d3 += __shfl_xor(d3, m, 64);
        if (lane == 0) { r2[tid >> 6] = s2; r3[tid >> 6] = d3; }
        __syncthreads();
        if (tid == 0) {
            l2part[pb] = r2[0] + r2[1] + r2[2] + r2[3];
            l3part[pb] = r3[0] + r3[1] + r3[2] + r3[3];
        }
    } else {
        // ---- zero hist + gsum ----
        unsigned* z = (unsigned*)(base + ZERO_OFF);
        const int n = (int)(ZERO_LEN / 4);
        for (int i2 = (blk - 3072) * TPB + tid; i2 < n; i2 += 8 * TPB) z[i2] = 0u;
    }
}

// ---------------- fused MFMA cost GEMM + single-pass histogram (R12 core, proven) ----------------
// 128x128 tile, 512 thr = 8 waves (2x4), wave tile 64x32; cos plain bf16 K=512
// (8 rounds), scores split-bf16 (2 rounds); prefetch-distance-2, 4x32KB LDS bufs,
// counted vmcnt(8), setprio. Epilogue reuses staging LDS: 8 count copies (one per
// wave) + 4 sum copies (per wave-pair) -> no cross-wave same-address contention.
__global__ __launch_bounds__(CTPB, 1) void cost_pass(
    const unsigned short* __restrict__ ahi,
    const unsigned short* __restrict__ h1hi, const unsigned short* __restrict__ h1lo,
    const unsigned short* __restrict__ h2hi, const unsigned short* __restrict__ h2lo,
    const float* __restrict__ d1,
    unsigned* __restrict__ hist, double* __restrict__ gsum)
{
    __shared__ char lds_raw[131072];  // 4 bufs x 32KB; reused by epilogue hists
    __shared__ float sD1[128];
    const int tid  = threadIdx.x;
    const int lane = tid & 63;
    const int wid  = tid >> 6;        // 0..7
    const int wr   = wid >> 2;        // 0..1 : 64-row band
    const int wc   = wid & 3;         // 0..3 : 32-col band

    // per-XCD 8x16 chunk (1024 blocks; HW round-robins blockIdx%8 across XCDs)
    const int orig = (int)blockIdx.x;
    const int xcd  = orig & 7;
    const int idx  = orig >> 3;             // 0..127
    const int bi   = (((xcd >> 1) << 3) + (idx & 7)) << 7;
    const int bj   = (((xcd & 1) << 4) + (idx >> 3)) << 7;

    f32x4 accC[4][2], accS[4][2];
    #pragma unroll
    for (int m = 0; m < 4; ++m)
        #pragma unroll
        for (int n = 0; n < 2; ++n)
            #pragma unroll
            for (int q = 0; q < 4; ++q) { accC[m][n][q] = 0.f; accS[m][n][q] = 0.f; }

    auto STAGE = [&](int t) {
        char* d = lds_raw + ((size_t)(t & 3) << 15);
        if (t < 8) {
            const int k0b = t << 7;                  // 64 bf16 = 128B per round
            #pragma unroll
            for (int q = 0; q < 2; ++q) {
                int o    = (q << 13) + (tid << 4);   // 0..16383
                int row  = o >> 7;
                int slot = (o >> 4) & 7;
                int sc   = (slot ^ (row & 7)) << 4;  // inverse swizzle on global src
                gload16((const char*)ahi + (size_t)(bi + row) * 1024 + k0b + sc, d + o);
                gload16((const char*)ahi + (size_t)(bj + row) * 1024 + k0b + sc, d + 16384 + o);
            }
        } else {
            const int k0b = (t - 8) << 6;            // 32 bf16 = 64B per round
            int o    = tid << 4;
            int row  = o >> 6;                       // tid>>2
            int slot = (o >> 4) & 3;                 // tid&3
            int sc   = (slot ^ ((row >> 1) & 3)) << 4;
            size_t ra = (size_t)(bi + row) * 128 + k0b + sc;
            size_t rb = (size_t)(bj + row) * 128 + k0b + sc;
            gload16((const char*)h1hi + ra, d + o);
            gload16((const char*)h1lo + ra, d + 8192 + o);
            gload16((const char*)h2hi + rb, d + 16384 + o);
            gload16((const char*)h2lo + rb, d + 24576 + o);
        }
    };

    STAGE(0);
    STAGE(1);
    #pragma unroll 1
    for (int t = 0; t < 10; ++t) {
        if (t < 8) STAGE(t + 2);
        __builtin_amdgcn_sched_barrier(0);
        if (t < 8)       asm volatile("s_waitcnt vmcnt(8)" ::: "memory");
        else if (t == 8) asm volatile("s_waitcnt vmcnt(4)" ::: "memory");
        else             asm volatile("s_waitcnt vmcnt(0)" ::: "memory");
        __builtin_amdgcn_s_barrier();
        const char* bufb = lds_raw + ((size_t)(t & 3) << 15);
        if (t < 8) {
            // cos: [128][128B] tiles, slot swizzle p ^ (row&7)
            #pragma unroll
            for (int ks = 0; ks < 2; ++ks) {
                bf16x8 a_[4], b_[2];
                const int pbase = (ks << 2) + (lane >> 4);
                #pragma unroll
                for (int m = 0; m < 4; ++m) {
                    int row = wr * 64 + m * 16 + (lane & 15);
                    a_[m] = *(const bf16x8*)(bufb + row * 128 + ((pbase ^ (lane & 7)) << 4));
                }
                #pragma unroll
                for (int n = 0; n < 2; ++n) {
                    int row = wc * 32 + n * 16 + (lane & 15);
                    b_[n] = *(const bf16x8*)(bufb + 16384 + row * 128 + ((pbase ^ (lane & 7)) << 4));
                }
                __builtin_amdgcn_s_setprio(1);
                #pragma unroll
                for (int m = 0; m < 4; ++m)
                    #pragma unroll
                    for (int n = 0; n < 2; ++n)
                        accC[m][n] = __builtin_amdgcn_mfma_f32_16x16x32_bf16(a_[m], b_[n], accC[m][n], 0, 0, 0);
                __builtin_amdgcn_s_setprio(0);
            }
        } else {
            // scores: [128][64B] tiles
            const int rdsw = (((lane >> 4) ^ ((lane >> 1) & 3)) << 4);
            bf16x8 ah[4], bh[2], bl[2];
            #pragma unroll
            for (int m = 0; m < 4; ++m)
                ah[m] = *(const bf16x8*)(bufb + (size_t)(wr * 64 + m * 16 + (lane & 15)) * 64 + rdsw);
            #pragma unroll
            for (int n = 0; n < 2; ++n) {
                bh[n] = *(const bf16x8*)(bufb + 16384 + (size_t)(wc * 32 + n * 16 + (lane & 15)) * 64 + rdsw);
                bl[n] = *(const bf16x8*)(bufb + 24576 + (size_t)(wc * 32 + n * 16 + (lane & 15)) * 64 + rdsw);
            }
            __builtin_amdgcn_s_setprio(1);
            #pragma unroll
            for (int m = 0; m < 4; ++m)
                #pragma unroll
                for (int n = 0; n < 2; ++n) {
                    accS[m][n] = __builtin_amdgcn_mfma_f32_16x16x32_bf16(ah[m], bh[n], accS[m][n], 0, 0, 0);
                    accS[m][n] = __builtin_amdgcn_mfma_f32_16x16x32_bf16(ah[m], bl[n], accS[m][n], 0, 0, 0);
                }
            __builtin_amdgcn_s_setprio(0);
            bf16x8 al[4];
            #pragma unroll
            for (int m = 0; m < 4; ++m)
                al[m] = *(const bf16x8*)(bufb + 8192 + (size_t)(wr * 64 + m * 16 + (lane & 15)) * 64 + rdsw);
            __builtin_amdgcn_s_setprio(1);
            #pragma unroll
            for (int m = 0; m < 4; ++m)
                #pragma unroll
                for (int n = 0; n < 2; ++n)
                    accS[m][n] = __builtin_amdgcn_mfma_f32_16x16x32_bf16(al[m], bh[n], accS[m][n], 0, 0, 0);
            __builtin_amdgcn_s_setprio(0);
        }
        __builtin_amdgcn_sched_barrier(0);
    }

    // epilogue: issue sD1 load early, then reuse staging LDS for hists
    float d1v = (tid < 128) ? d1[bi + tid] : 0.f;   // global load before reuse barrier
    __syncthreads();                                 // all staging ds_reads done
    unsigned* lh = (unsigned*)lds_raw;               // 8 count copies: [0..2048)x8 = 64KB
    float*    ls = (float*)(lds_raw + 65536);        // 4 sum copies:   [0..2048)x4 = 32KB
    if (tid < 128) sD1[tid] = d1v;
    for (int q = tid; q < 16384; q += CTPB) lh[q] = 0u;
    for (int q = tid; q < 8192; q += CTPB) ls[q] = 0.f;
    __syncthreads();
    unsigned* lhW = lh + wid * 2048;                 // private count copy per wave
    float*    lsW = ls + (wid >> 1) * 2048;          // sum copy per wave-pair
    const unsigned CB = __float_as_uint(1e-8f);
    unsigned nclamp = 0;
    #pragma unroll
    for (int m = 0; m < 4; ++m) {
        #pragma unroll
        for (int r = 0; r < 4; ++r) {
            const int irow = wr * 64 + m * 16 + (lane >> 4) * 4 + r;
            const int i = bi + irow;
            const float di = sD1[irow];
            #pragma unroll
            for (int n = 0; n < 2; ++n) {
                const int j = bj + wc * 32 + n * 16 + (lane & 15);
                float cosv = fminf(fmaxf(accC[m][n][r], 1e-6f), 0.999999f);
                float v = (1.0f - cosv) * 0.2f + accS[m][n][r] - di;
                v = fmaxf(v, 1e-8f);
                if (i == j) v = 0.0f;
                unsigned bits = __float_as_uint(v);
                if (bits == CB) ++nclamp;
                else {
                    atomicAdd(&lhW[bits >> 21], 1u);
                    atomicAdd(&lsW[bits >> 21], v);
                }
            }
        }
    }
    if (nclamp) {
        atomicAdd(&lhW[CB >> 21], nclamp);
        atomicAdd(&lsW[CB >> 21], (float)((double)nclamp * 1e-8));
    }
    __syncthreads();
    for (int q = tid; q < 2048; q += CTPB) {
        unsigned c = 0;
        #pragma unroll
        for (int cp = 0; cp < 8; ++cp) c += lh[cp * 2048 + q];
        if (c) atomicAdd(&hist[q], c);
        float s = ls[q] + ls[2048 + q] + ls[4096 + q] + ls[6144 + q];
        if (s != 0.f) atomicAdd(&gsum[q], (double)s);
    }
}

// ---------------- final: scan histogram, reduce partials, assemble losses ----------------
__global__ __launch_bounds__(TPB) void scan_final(
    const unsigned* __restrict__ hist, const double* __restrict__ gsum,
    const int* __restrict__ epochs_ptr, const double* __restrict__ l2part,
    const double* __restrict__ l3part, float* __restrict__ out)
{
    const int tid = threadIdx.x;
    __shared__ unsigned wtot[4];
    __shared__ int sbin;
    __shared__ unsigned srem;
    __shared__ double dred[4], dred2[4], dred3[4];

    // k from epochs
    int e = epochs_ptr[0];
    if (e > 1000000 || e < 0) e = (int)__int_as_float(e);
    double cr = (double)e * 0.1;
    if (!(cr < 1.0)) cr = 0.99;
    double kd = ceil(16777216.0 * (1.0 - cr));
    if (kd < 1.0) kd = 1.0;
    if (kd > 16777216.0) kd = 16777216.0;
    unsigned k = (unsigned)kd;

    unsigned local[8];
    unsigned s = 0;
    #pragma unroll
    for (int r = 0; r < 8; ++r) { unsigned v = hist[tid * 8 + r]; local[r] = v; s += v; }
    unsigned inc = s;
    #pragma unroll
    for (int d = 1; d < 64; d <<= 1) {
        unsigned n = __shfl_up(inc, (unsigned)d, 64);
        if ((tid & 63) >= d) inc += n;
    }
    if ((tid & 63) == 63) wtot[tid >> 6] = inc;
    __syncthreads();
    unsigned woff = 0;
    for (int wv = 0; wv < (tid >> 6); ++wv) woff += wtot[wv];
    unsigned excl = woff + (inc - s);
    if (k > excl && k <= excl + s) {
        unsigned rem = k - excl;
        int bin = tid * 8;
        #pragma unroll
        for (int r = 0; r < 8; ++r) {
            if (rem <= local[r]) { bin = tid * 8 + r; break; }
            rem -= local[r];
        }
        sbin = bin; srem = rem;
    }
    __syncthreads();
    const int b1 = sbin;
    double s3 = 0.0, p2 = 0.0, p3 = 0.0;
    for (int q = tid; q < 2048; q += TPB) if (q < b1) s3 += gsum[q];
    for (int q = tid; q < 1024; q += TPB) { p2 += l2part[q]; p3 += l3part[q]; }
    #pragma unroll
    for (int off = 32; off; off >>= 1) {
        s3 += __shfl_down(s3, off, 64);
        p2 += __shfl_down(p2, off, 64);
        p3 += __shfl_down(p3, off, 64);
    }
    if ((tid & 63) == 0) { dred[tid >> 6] = s3; dred2[tid >> 6] = p2; dred3[tid >> 6] = p3; }
    __syncthreads();
    if (tid == 0) {
        double S1 = dred[0] + dred[1] + dred[2] + dred[3];
        double sum2 = dred2[0] + dred2[1] + dred2[2] + dred2[3];
        double sum3 = dred3[0] + dred3[1] + dred3[2] + dred3[3];
        unsigned cnt = hist[b1];
        unsigned rem = srem;
        double avg = (cnt > 0) ? (gsum[b1] / (double)cnt) : 0.0;
        double loss1 = S1 + (double)(rem - 1) * avg;   // sum of (k-1) smallest values
        double loss2 = -sum2 / (64.0 * 4096.0);
        double loss3 = sum3;
        double total = 0.5 * loss1 + 0.5 * loss2 + 0.5 * loss3
                     + 3.0 * 0.69314718055994530942;
        float v = (float)total;
        unsigned bits = __float_as_uint(v);
        unsigned lsb = (bits >> 16) & 1u;
        unsigned h = (bits + 0x7FFFu + lsb) >> 16;
        ((unsigned*)out)[0] = (bits & 0xFFFF0000u) | (h & 0xFFFFu);
    }
}

extern "C" void kernel_launch(void* const* d_in, const int* in_sizes, int n_in,
                              void* d_out, int out_size, void* d_ws, size_t ws_size,
                              hipStream_t stream) {
    const float* h1f  = (const float*)d_in[0];
    const float* h2f  = (const float*)d_in[1];
    const float* caps = (const float*)d_in[2];
    const float* sim  = (const float*)d_in[3];
    const float* sv   = (const float*)d_in[4];
    const float* sv2  = (const float*)d_in[5];
    const int*   ep   = (const int*)d_in[6];

    char* base = (char*)d_ws;
    unsigned short* AHI  = (unsigned short*)(base + OFF_AHI);
    float*    D1   = (float*)(base + OFF_D1);
    unsigned* H1   = (unsigned*)(base + OFF_H1);
    double*   GS1  = (double*)(base + OFF_GS1);
    double*   L2P  = (double*)(base + OFF_L2P);
    double*   L3P  = (double*)(base + OFF_L3P);
    unsigned short* H1HI = (unsigned short*)(base + OFF_HS);
    unsigned short* H1LO = (unsigned short*)(base + OFF_HS + HS_ONE);
    unsigned short* H2HI = (unsigned short*)(base + OFF_HS + 2 * HS_ONE);
    unsigned short* H2LO = (unsigned short*)(base + OFF_HS + 3 * HS_ONE);

    front_k<<<3080, TPB, 0, stream>>>(caps, sim, AHI, h1f, h2f,
                                      H1HI, H1LO, H2HI, H2LO, D1, sv, sv2,
                                      L2P, L3P, base);
    cost_pass<<<1024, CTPB, 0, stream>>>(AHI, H1HI, H1LO, H2HI, H2LO, D1, H1, GS1);
    scan_final<<<1, TPB, 0, stream>>>(H1, GS1, ep, L2P, L3P, (float*)d_out);
}

// Round 16
// 151.156 us; speedup vs baseline: 1.0350x; 1.0350x over previous
//
#include <hip/hip_runtime.h>
#include <hip/hip_bf16.h>

#define TPB 256
#define CTPB 512

using f32x4  = __attribute__((ext_vector_type(4))) float;
using bf16x8 = __attribute__((ext_vector_type(8))) short;

// Problem constants (B=4096, L=32, E=512, D=64)
static constexpr int BB = 4096;

// Workspace layout (bytes)
static constexpr size_t OFF_AHI  = 0;                        // a_hi [B][512] bf16 = 4 MB
static constexpr size_t OFF_D1   = 8388608;                  // d1 [B] f32 = 16 KB
static constexpr size_t OFF_H1   = OFF_D1 + 16384;           // hist u32[2048] = 8 KB
static constexpr size_t OFF_GS1  = OFF_H1 + 8192;            // gsum f64[2048] = 16 KB
static constexpr size_t OFF_L2P  = OFF_GS1 + 16384;          // loss2 partials f64[1024]
static constexpr size_t OFF_L3P  = OFF_L2P + 8192;           // loss3 partials f64[1024]
static constexpr size_t OFF_HS   = OFF_L3P + 8192;           // h1hi,h1lo,h2hi,h2lo bf16 [B][64]
static constexpr size_t HS_ONE   = (size_t)BB * 64 * 2;      // 512 KB
static constexpr size_t ZERO_OFF = OFF_H1;
static constexpr size_t ZERO_LEN = OFF_L2P - OFF_H1;         // 24576 B (hist + gsum only)

// ---------------- helpers ----------------
__device__ __forceinline__ void bsplit(float x, unsigned short& h, unsigned short& l)
{
    unsigned b = __float_as_uint(x);
    unsigned r = (b + 0x7FFFu + ((b >> 16) & 1u)) >> 16;       // rne bf16
    h = (unsigned short)r;
    float hf = __uint_as_float(r << 16);
    float lof = x - hf;                                        // exact in f32
    unsigned b2 = __float_as_uint(lof);
    unsigned r2 = (b2 + 0x7FFFu + ((b2 >> 16) & 1u)) >> 16;
    l = (unsigned short)r2;
}

__device__ __forceinline__ unsigned short b2h(float x)
{
    unsigned b = __float_as_uint(x);
    return (unsigned short)((b + 0x7FFFu + ((b >> 16) & 1u)) >> 16);
}

__device__ __forceinline__ void gload16(const void* g, void* l)
{
    __builtin_amdgcn_global_load_lds((const __attribute__((address_space(1))) void*)g,
                                     (__attribute__((address_space(3))) void*)l,
                                     16, 0, 0);
}

// ---------------- front: prep (blocks 0..4095) + small (4096..5119) + zero (5120..5127) ----------------
__global__ __launch_bounds__(TPB) void front_k(
    const float* __restrict__ caps, const float* __restrict__ sim,
    unsigned short* __restrict__ ahi,
    const float* __restrict__ h1f, const float* __restrict__ h2f,
    unsigned short* __restrict__ h1hi, unsigned short* __restrict__ h1lo,
    unsigned short* __restrict__ h2hi, unsigned short* __restrict__ h2lo,
    float* __restrict__ d1, const float* __restrict__ sv,
    const float* __restrict__ sv2, double* __restrict__ l2part,
    double* __restrict__ l3part, char* __restrict__ base)
{
    const int blk = (int)blockIdx.x;
    const int tid = threadIdx.x;
    __shared__ float sm[32];
    __shared__ float w[32];
    __shared__ float red[4];
    __shared__ float nrm;
    __shared__ double r2[4], r3[4];

    if (blk < 4096) {
        // ---- prep: softmax(sim) -> caps_mean -> normalized a (bf16) ----
        const int b = blk;
        if (tid < 32) sm[tid] = sim[b * 32 + tid];
        __syncthreads();
        if (tid < 32) {
            float m = -1e30f;
            for (int l = 0; l < 32; ++l) m = fmaxf(m, sm[l]);
            float ssum = 0.f;
            for (int l = 0; l < 32; ++l) ssum += expf(sm[l] - m);
            w[tid] = expf(sm[tid] - m) / ssum;
        }
        __syncthreads();
        const float2* cb2 = (const float2*)(caps + (size_t)b * 32 * 512);
        float cx = 0.f, cy = 0.f;
        for (int l = 0; l < 32; ++l) {
            float wl = w[l];
            float2 v = cb2[l * 256 + tid];
            cx = fmaf(wl, v.x, cx);
            cy = fmaf(wl, v.y, cy);
        }
        float ss = cx * cx + cy * cy;
        #pragma unroll
        for (int off = 32; off; off >>= 1) ss += __shfl_down(ss, off, 64);
        if ((tid & 63) == 0) red[tid >> 6] = ss;
        __syncthreads();
        if (tid == 0) nrm = sqrtf(red[0] + red[1] + red[2] + red[3]);
        __syncthreads();
        float an = fmaxf(nrm, 1e-5f);
        ahi[(size_t)b * 512 + 2 * tid]     = b2h(cx / an);
        ahi[(size_t)b * 512 + 2 * tid + 1] = b2h(cy / an);
    } else if (blk < 5120) {
        // ---- small: splith + diag + loss2/loss3 partials (4 rows / block) ----
        const int pb   = blk - 4096;
        const int row  = (pb << 2) + (tid >> 6);
        const int lane = tid & 63;
        const int i    = (row << 6) + lane;
        float x1 = h1f[i], x2 = h2f[i];
        unsigned short h, l;
        bsplit(x1, h, l); h1hi[i] = h; h1lo[i] = l;
        bsplit(x2, h, l); h2hi[i] = h; h2lo[i] = l;
        float p = x1 * x2;
        #pragma unroll
        for (int m = 32; m; m >>= 1) p += __shfl_xor(p, m, 64);
        if (lane == 0) d1[row] = p;
        float xq = x1 - 0.5f;
        double s2 = (double)(xq * xq);
        #pragma unroll
        for (int m = 32; m; m >>= 1) s2 += __shfl_xor(s2, m, 64);
        float xt = sv[i] / 0.1f;
        float xs = sv2[i] / 0.1f;
        float mt = xt, ms = xs;
        #pragma unroll
        for (int m = 32; m; m >>= 1) {
            mt = fmaxf(mt, __shfl_xor(mt, m, 64));
            ms = fmaxf(ms, __shfl_xor(ms, m, 64));
        }
        float et = expf(xt - mt), es = expf(xs - ms);
        float sst = et, sss = es;
        #pragma unroll
        for (int m = 32; m; m >>= 1) { sst += __shfl_xor(sst, m, 64); sss += __shfl_xor(sss, m, 64); }
        float pt = (xt - mt) - logf(sst);
        float ps = (xs - ms) - logf(sss);
        double d3 = (double)((et / sst) * (pt - ps));
        #pragma unroll
        for (int m = 32; m; m >>= 1) d3 += __shfl_xor(d3, m, 64);
        if (lane == 0) { r2[tid >> 6] = s2; r3[tid >> 6] = d3; }
        __syncthreads();
        if (tid == 0) {
            l2part[pb] = r2[0] + r2[1] + r2[2] + r2[3];
            l3part[pb] = r3[0] + r3[1] + r3[2] + r3[3];
        }
    } else {
        // ---- zero hist + gsum ----
        unsigned* z = (unsigned*)(base + ZERO_OFF);
        const int n = (int)(ZERO_LEN / 4);
        for (int i2 = (blk - 5120) * TPB + tid; i2 < n; i2 += 8 * TPB) z[i2] = 0u;
    }
}

// ---------------- fused MFMA cost GEMM + single-pass histogram (R12 core, proven) ----------------
// 128x128 tile, 512 thr = 8 waves (2x4), wave tile 64x32; cos plain bf16 K=512
// (8 rounds), scores split-bf16 (2 rounds); prefetch-distance-2, 4x32KB LDS bufs,
// counted vmcnt(8), setprio. Epilogue reuses staging LDS: 4 count + 2 sum copies.
__global__ __launch_bounds__(CTPB, 1) void cost_pass(
    const unsigned short* __restrict__ ahi,
    const unsigned short* __restrict__ h1hi, const unsigned short* __restrict__ h1lo,
    const unsigned short* __restrict__ h2hi, const unsigned short* __restrict__ h2lo,
    const float* __restrict__ d1,
    unsigned* __restrict__ hist, double* __restrict__ gsum)
{
    __shared__ char lds_raw[131072];  // 4 bufs x 32KB; reused by epilogue hists
    __shared__ float sD1[128];
    const int tid  = threadIdx.x;
    const int lane = tid & 63;
    const int wid  = tid >> 6;        // 0..7
    const int wr   = wid >> 2;        // 0..1 : 64-row band
    const int wc   = wid & 3;         // 0..3 : 32-col band

    // per-XCD 8x16 chunk (1024 blocks; HW round-robins blockIdx%8 across XCDs)
    const int orig = (int)blockIdx.x;
    const int xcd  = orig & 7;
    const int idx  = orig >> 3;             // 0..127
    const int bi   = (((xcd >> 1) << 3) + (idx & 7)) << 7;
    const int bj   = (((xcd & 1) << 4) + (idx >> 3)) << 7;

    f32x4 accC[4][2], accS[4][2];
    #pragma unroll
    for (int m = 0; m < 4; ++m)
        #pragma unroll
        for (int n = 0; n < 2; ++n)
            #pragma unroll
            for (int q = 0; q < 4; ++q) { accC[m][n][q] = 0.f; accS[m][n][q] = 0.f; }

    auto STAGE = [&](int t) {
        char* d = lds_raw + ((size_t)(t & 3) << 15);
        if (t < 8) {
            const int k0b = t << 7;                  // 64 bf16 = 128B per round
            #pragma unroll
            for (int q = 0; q < 2; ++q) {
                int o    = (q << 13) + (tid << 4);   // 0..16383
                int row  = o >> 7;
                int slot = (o >> 4) & 7;
                int sc   = (slot ^ (row & 7)) << 4;  // inverse swizzle on global src
                gload16((const char*)ahi + (size_t)(bi + row) * 1024 + k0b + sc, d + o);
                gload16((const char*)ahi + (size_t)(bj + row) * 1024 + k0b + sc, d + 16384 + o);
            }
        } else {
            const int k0b = (t - 8) << 6;            // 32 bf16 = 64B per round
            int o    = tid << 4;
            int row  = o >> 6;                       // tid>>2
            int slot = (o >> 4) & 3;                 // tid&3
            int sc   = (slot ^ ((row >> 1) & 3)) << 4;
            size_t ra = (size_t)(bi + row) * 128 + k0b + sc;
            size_t rb = (size_t)(bj + row) * 128 + k0b + sc;
            gload16((const char*)h1hi + ra, d + o);
            gload16((const char*)h1lo + ra, d + 8192 + o);
            gload16((const char*)h2hi + rb, d + 16384 + o);
            gload16((const char*)h2lo + rb, d + 24576 + o);
        }
    };

    STAGE(0);
    STAGE(1);
    #pragma unroll 1
    for (int t = 0; t < 10; ++t) {
        if (t < 8) STAGE(t + 2);
        __builtin_amdgcn_sched_barrier(0);
        if (t < 8)       asm volatile("s_waitcnt vmcnt(8)" ::: "memory");
        else if (t == 8) asm volatile("s_waitcnt vmcnt(4)" ::: "memory");
        else             asm volatile("s_waitcnt vmcnt(0)" ::: "memory");
        __builtin_amdgcn_s_barrier();
        const char* bufb = lds_raw + ((size_t)(t & 3) << 15);
        if (t < 8) {
            // cos: [128][128B] tiles, slot swizzle p ^ (row&7)
            #pragma unroll
            for (int ks = 0; ks < 2; ++ks) {
                bf16x8 a_[4], b_[2];
                const int pbase = (ks << 2) + (lane >> 4);
                #pragma unroll
                for (int m = 0; m < 4; ++m) {
                    int row = wr * 64 + m * 16 + (lane & 15);
                    a_[m] = *(const bf16x8*)(bufb + row * 128 + ((pbase ^ (lane & 7)) << 4));
                }
                #pragma unroll
                for (int n = 0; n < 2; ++n) {
                    int row = wc * 32 + n * 16 + (lane & 15);
                    b_[n] = *(const bf16x8*)(bufb + 16384 + row * 128 + ((pbase ^ (lane & 7)) << 4));
                }
                __builtin_amdgcn_s_setprio(1);
                #pragma unroll
                for (int m = 0; m < 4; ++m)
                    #pragma unroll
                    for (int n = 0; n < 2; ++n)
                        accC[m][n] = __builtin_amdgcn_mfma_f32_16x16x32_bf16(a_[m], b_[n], accC[m][n], 0, 0, 0);
                __builtin_amdgcn_s_setprio(0);
            }
        } else {
            // scores: [128][64B] tiles
            const int rdsw = (((lane >> 4) ^ ((lane >> 1) & 3)) << 4);
            bf16x8 ah[4], bh[2], bl[2];
            #pragma unroll
            for (int m = 0; m < 4; ++m)
                ah[m] = *(const bf16x8*)(bufb + (size_t)(wr * 64 + m * 16 + (lane & 15)) * 64 + rdsw);
            #pragma unroll
            for (int n = 0; n < 2; ++n) {
                bh[n] = *(const bf16x8*)(bufb + 16384 + (size_t)(wc * 32 + n * 16 + (lane & 15)) * 64 + rdsw);
                bl[n] = *(const bf16x8*)(bufb + 24576 + (size_t)(wc * 32 + n * 16 + (lane & 15)) * 64 + rdsw);
            }
            __builtin_amdgcn_s_setprio(1);
            #pragma unroll
            for (int m = 0; m < 4; ++m)
                #pragma unroll
                for (int n = 0; n < 2; ++n) {
                    accS[m][n] = __builtin_amdgcn_mfma_f32_16x16x32_bf16(ah[m], bh[n], accS[m][n], 0, 0, 0);
                    accS[m][n] = __builtin_amdgcn_mfma_f32_16x16x32_bf16(ah[m], bl[n], accS[m][n], 0, 0, 0);
                }
            __builtin_amdgcn_s_setprio(0);
            bf16x8 al[4];
            #pragma unroll
            for (int m = 0; m < 4; ++m)
                al[m] = *(const bf16x8*)(bufb + 8192 + (size_t)(wr * 64 + m * 16 + (lane & 15)) * 64 + rdsw);
            __builtin_amdgcn_s_setprio(1);
            #pragma unroll
            for (int m = 0; m < 4; ++m)
                #pragma unroll
                for (int n = 0; n < 2; ++n)
                    accS[m][n] = __builtin_amdgcn_mfma_f32_16x16x32_bf16(al[m], bh[n], accS[m][n], 0, 0, 0);
            __builtin_amdgcn_s_setprio(0);
        }
        __builtin_amdgcn_sched_barrier(0);
    }

    // epilogue: all staging reads done -> barrier -> reuse staging LDS for hists
    __syncthreads();
    unsigned* lh = (unsigned*)lds_raw;          // 4 count copies: [0..2048)x4
    float*    ls = (float*)(lds_raw + 32768);   // 2 sum copies:   [0..2048)x2
    if (tid < 128) sD1[tid] = d1[bi + tid];
    for (int q = tid; q < 8192; q += CTPB) lh[q] = 0u;
    for (int q = tid; q < 4096; q += CTPB) ls[q] = 0.f;
    __syncthreads();
    unsigned* lhW = lh + (wid >> 1) * 2048;     // waves {0,1}{2,3}{4,5}{6,7} share
    float*    lsW = ls + (wid >> 2) * 2048;     // 4-wave halves share
    const unsigned CB = __float_as_uint(1e-8f);
    unsigned nclamp = 0;
    #pragma unroll
    for (int m = 0; m < 4; ++m) {
        #pragma unroll
        for (int r = 0; r < 4; ++r) {
            const int irow = wr * 64 + m * 16 + (lane >> 4) * 4 + r;
            const int i = bi + irow;
            const float di = sD1[irow];
            #pragma unroll
            for (int n = 0; n < 2; ++n) {
                const int j = bj + wc * 32 + n * 16 + (lane & 15);
                float cosv = fminf(fmaxf(accC[m][n][r], 1e-6f), 0.999999f);
                float v = (1.0f - cosv) * 0.2f + accS[m][n][r] - di;
                v = fmaxf(v, 1e-8f);
                if (i == j) v = 0.0f;
                unsigned bits = __float_as_uint(v);
                if (bits == CB) ++nclamp;
                else {
                    atomicAdd(&lhW[bits >> 21], 1u);
                    atomicAdd(&lsW[bits >> 21], v);
                }
            }
        }
    }
    if (nclamp) {
        atomicAdd(&lhW[CB >> 21], nclamp);
        atomicAdd(&lsW[CB >> 21], (float)((double)nclamp * 1e-8));
    }
    __syncthreads();
    for (int q = tid; q < 2048; q += CTPB) {
        unsigned c = lh[q] + lh[2048 + q] + lh[4096 + q] + lh[6144 + q];
        if (c) atomicAdd(&hist[q], c);
        float s = ls[q] + ls[2048 + q];
        if (s != 0.f) atomicAdd(&gsum[q], (double)s);
    }
}

// ---------------- final: scan histogram, reduce partials, assemble losses ----------------
__global__ __launch_bounds__(TPB) void scan_final(
    const unsigned* __restrict__ hist, const double* __restrict__ gsum,
    const int* __restrict__ epochs_ptr, const double* __restrict__ l2part,
    const double* __restrict__ l3part, float* __restrict__ out)
{
    const int tid = threadIdx.x;
    __shared__ unsigned wtot[4];
    __shared__ int sbin;
    __shared__ unsigned srem;
    __shared__ double dred[4], dred2[4], dred3[4];

    // k from epochs
    int e = epochs_ptr[0];
    if (e > 1000000 || e < 0) e = (int)__int_as_float(e);
    double cr = (double)e * 0.1;
    if (!(cr < 1.0)) cr = 0.99;
    double kd = ceil(16777216.0 * (1.0 - cr));
    if (kd < 1.0) kd = 1.0;
    if (kd > 16777216.0) kd = 16777216.0;
    unsigned k = (unsigned)kd;

    unsigned local[8];
    unsigned s = 0;
    #pragma unroll
    for (int r = 0; r < 8; ++r) { unsigned v = hist[tid * 8 + r]; local[r] = v; s += v; }
    unsigned inc = s;
    #pragma unroll
    for (int d = 1; d < 64; d <<= 1) {
        unsigned n = __shfl_up(inc, (unsigned)d, 64);
        if ((tid & 63) >= d) inc += n;
    }
    if ((tid & 63) == 63) wtot[tid >> 6] = inc;
    __syncthreads();
    unsigned woff = 0;
    for (int wv = 0; wv < (tid >> 6); ++wv) woff += wtot[wv];
    unsigned excl = woff + (inc - s);
    if (k > excl && k <= excl + s) {
        unsigned rem = k - excl;
        int bin = tid * 8;
        #pragma unroll
        for (int r = 0; r < 8; ++r) {
            if (rem <= local[r]) { bin = tid * 8 + r; break; }
            rem -= local[r];
        }
        sbin = bin; srem = rem;
    }
    __syncthreads();
    const int b1 = sbin;
    double s3 = 0.0, p2 = 0.0, p3 = 0.0;
    for (int q = tid; q < 2048; q += TPB) if (q < b1) s3 += gsum[q];
    for (int q = tid; q < 1024; q += TPB) { p2 += l2part[q]; p3 += l3part[q]; }
    #pragma unroll
    for (int off = 32; off; off >>= 1) {
        s3 += __shfl_down(s3, off, 64);
        p2 += __shfl_down(p2, off, 64);
        p3 += __shfl_down(p3, off, 64);
    }
    if ((tid & 63) == 0) { dred[tid >> 6] = s3; dred2[tid >> 6] = p2; dred3[tid >> 6] = p3; }
    __syncthreads();
    if (tid == 0) {
        double S1 = dred[0] + dred[1] + dred[2] + dred[3];
        double sum2 = dred2[0] + dred2[1] + dred2[2] + dred2[3];
        double sum3 = dred3[0] + dred3[1] + dred3[2] + dred3[3];
        unsigned cnt = hist[b1];
        unsigned rem = srem;
        double avg = (cnt > 0) ? (gsum[b1] / (double)cnt) : 0.0;
        double loss1 = S1 + (double)(rem - 1) * avg;   // sum of (k-1) smallest values
        double loss2 = -sum2 / (64.0 * 4096.0);
        double loss3 = sum3;
        double total = 0.5 * loss1 + 0.5 * loss2 + 0.5 * loss3
                     + 3.0 * 0.69314718055994530942;
        float v = (float)total;
        unsigned bits = __float_as_uint(v);
        unsigned lsb = (bits >> 16) & 1u;
        unsigned h = (bits + 0x7FFFu + lsb) >> 16;
        ((unsigned*)out)[0] = (bits & 0xFFFF0000u) | (h & 0xFFFFu);
    }
}

extern "C" void kernel_launch(void* const* d_in, const int* in_sizes, int n_in,
                              void* d_out, int out_size, void* d_ws, size_t ws_size,
                              hipStream_t stream) {
    const float* h1f  = (const float*)d_in[0];
    const float* h2f  = (const float*)d_in[1];
    const float* caps = (const float*)d_in[2];
    const float* sim  = (const float*)d_in[3];
    const float* sv   = (const float*)d_in[4];
    const float* sv2  = (const float*)d_in[5];
    const int*   ep   = (const int*)d_in[6];

    char* base = (char*)d_ws;
    unsigned short* AHI  = (unsigned short*)(base + OFF_AHI);
    float*    D1   = (float*)(base + OFF_D1);
    unsigned* H1   = (unsigned*)(base + OFF_H1);
    double*   GS1  = (double*)(base + OFF_GS1);
    double*   L2P  = (double*)(base + OFF_L2P);
    double*   L3P  = (double*)(base + OFF_L3P);
    unsigned short* H1HI = (unsigned short*)(base + OFF_HS);
    unsigned short* H1LO = (unsigned short*)(base + OFF_HS + HS_ONE);
    unsigned short* H2HI = (unsigned short*)(base + OFF_HS + 2 * HS_ONE);
    unsigned short* H2LO = (unsigned short*)(base + OFF_HS + 3 * HS_ONE);

    front_k<<<5128, TPB, 0, stream>>>(caps, sim, AHI, h1f, h2f,
                                      H1HI, H1LO, H2HI, H2LO, D1, sv, sv2,
                                      L2P, L3P, base);
    cost_pass<<<1024, CTPB, 0, stream>>>(AHI, H1HI, H1LO, H2HI, H2LO, D1, H1, GS1);
    scan_final<<<1, TPB, 0, stream>>>(H1, GS1, ep, L2P, L3P, (float*)d_out);
}